// Round 5
// baseline (359.327 us; speedup 1.0000x reference)
//
#include <hip/hip_runtime.h>

typedef __attribute__((ext_vector_type(4))) float f32x4;
typedef __attribute__((ext_vector_type(8))) __bf16 bf16x8;
typedef __attribute__((ext_vector_type(4))) __bf16 bf16x4;

__device__ __forceinline__ void gload_lds16(const __bf16* g, __bf16* l) {
  __builtin_amdgcn_global_load_lds(
      (const __attribute__((address_space(1))) unsigned int*)(g),
      (__attribute__((address_space(3))) unsigned int*)(l), 16, 0, 0);
}

// ---------------- prep: weight transposes + x convert + pad_or, one launch --------
__global__ __launch_bounds__(256) void prep(
    const float* __restrict__ Wq, const float* __restrict__ Wk,
    const float* __restrict__ Wv, const float* __restrict__ Wo,
    const float4* __restrict__ x, const unsigned long long* __restrict__ pad,
    __bf16* __restrict__ Wqkvt, __bf16* __restrict__ Wot,
    bf16x4* __restrict__ xb, unsigned char* __restrict__ pad64) {
  const int bx = blockIdx.x, by = blockIdx.y;
  const int tx = threadIdx.x, ty = threadIdx.y;
  const int tid = ty * 32 + tx;
  if (bx >= 160) {
    int i = ((bx - 160) * 64 + by) * 256 + tid;
    float4 v = x[i];
    bf16x4 o = {(__bf16)v.x, (__bf16)v.y, (__bf16)v.z, (__bf16)v.w};
    xb[i] = o;
    return;
  }
  if (bx == 0 && by == 0 && tid < 64) {
    unsigned long long acc = 0;
#pragma unroll
    for (int i = 0; i < 8; ++i) acc |= pad[tid * 8 + i];
    pad64[tid] = (acc != 0) ? 1 : 0;
  }
  __shared__ float t[32][33];
  const float* src; __bf16* dst; int ss, c0;
  if (bx < 64)      { src = Wq; dst = Wqkvt;                       ss = 2048; c0 = bx * 32; }
  else if (bx < 80) { src = Wk; dst = Wqkvt + (size_t)2048 * 2048; ss = 512;  c0 = (bx - 64) * 32; }
  else if (bx < 96) { src = Wv; dst = Wqkvt + (size_t)2560 * 2048; ss = 512;  c0 = (bx - 80) * 32; }
  else              { src = Wo; dst = Wot;                         ss = 2048; c0 = (bx - 96) * 32; }
  const int r0 = by * 32;
#pragma unroll
  for (int i = ty; i < 32; i += 8)
    t[i][tx] = src[(size_t)(r0 + i) * ss + c0 + tx];
  __syncthreads();
#pragma unroll
  for (int i = ty; i < 32; i += 8)
    dst[(size_t)(c0 + i) * 2048 + r0 + tx] = (__bf16)t[tx][i];
}

// ---------------- QKV GEMM + fused RMSNorm/RoPE/V-transpose, LDS-staged stores ----
// C = xb[4096][2048] * Wqkvt[3072][2048]^T, tile 128x128, grid (24, 32).
// jb 0-15: Q head (pre-scaled softmax_scale*log2e), 16-19: K head, 20-23: V (transposed).
// Wave col map: col = jj*32 + wnh + c15 so rotate-half pairs (d,d+64) = frags (jj,jj+2)
// stay in-wave. Epilogue stages the 128x128 output tile in LDS (stride 136, overlaid
// on As/Bs) and writes 16B-coalesced full lines (fixes R4's partial-line RMW stores).
__global__ __launch_bounds__(256) void gemm_qkv(
    const __bf16* __restrict__ A, const __bf16* __restrict__ Bt,
    const float* __restrict__ qw, const float* __restrict__ kw,
    const float* __restrict__ cosT, const float* __restrict__ sinT,
    __bf16* __restrict__ Qb, __bf16* __restrict__ Kb, __bf16* __restrict__ Vt) {
  __shared__ __align__(16) __bf16 smem[128 * 136];  // 34.8 KB: As|Bs during K-loop, stage after
  __shared__ float ssum[128][2];
  __bf16* As = smem;
  __bf16* Bs = smem + 128 * 32;
  __bf16* stage = smem;
  const int K = 2048;
  const int tid = threadIdx.x;
  const int lane = tid & 63;
  const int c15 = lane & 15, quad = lane >> 4;
  const int wm = ((tid >> 6) & 1) * 64;
  const int wnh = (tid >> 7) * 16;
  const int jb = blockIdx.x;
  const int m0 = blockIdx.y * 128, n0 = jb * 128;
  const int wbase = tid & 192;

  f32x4 acc[4][4] = {};

  const int row0 = tid >> 2, cc0 = (tid & 3) * 8;
  const int row1 = (tid + 256) >> 2;
  const __bf16* a0 = A + (size_t)(m0 + row0) * K + cc0;
  const __bf16* a1 = A + (size_t)(m0 + row1) * K + cc0;
  const __bf16* b0 = Bt + (size_t)(n0 + row0) * K + cc0;
  const __bf16* b1 = Bt + (size_t)(n0 + row1) * K + cc0;
  __bf16* lA0 = As + (size_t)wbase * 8;
  __bf16* lA1 = As + (size_t)(256 + wbase) * 8;
  __bf16* lB0 = Bs + (size_t)wbase * 8;
  __bf16* lB1 = Bs + (size_t)(256 + wbase) * 8;

  for (int k0 = 0; k0 < K; k0 += 32) {
    gload_lds16(a0 + k0, lA0);
    gload_lds16(a1 + k0, lA1);
    gload_lds16(b0 + k0, lB0);
    gload_lds16(b1 + k0, lB1);
    __syncthreads();
    bf16x8 af[4], bfr[4];
#pragma unroll
    for (int i = 0; i < 4; ++i) {
      af[i]  = *(const bf16x8*)(As + (wm + i * 16 + c15) * 32 + quad * 8);
      bfr[i] = *(const bf16x8*)(Bs + (i * 32 + wnh + c15) * 32 + quad * 8);
    }
#pragma unroll
    for (int i = 0; i < 4; ++i)
#pragma unroll
      for (int j = 0; j < 4; ++j)
        acc[i][j] = __builtin_amdgcn_mfma_f32_16x16x32_bf16(af[i], bfr[j], acc[i][j], 0, 0, 0);
    __syncthreads();
  }

  const int b = m0 >> 11;
  const int s0 = m0 & 2047;
  const int orow = tid >> 4, ocol = (tid & 15) * 8;  // coalesced out: 16 lanes = 256B row

  if (jb >= 20) {
    // V: stage[d][s_local] (stride 136), pack 4 consecutive s per ds_write_b64.
#pragma unroll
    for (int jj = 0; jj < 4; ++jj) {
      int d = jj * 32 + wnh + c15;
#pragma unroll
      for (int i = 0; i < 4; ++i) {
        int sl = wm + i * 16 + quad * 4;
        bf16x4 o = {(__bf16)acc[i][jj][0], (__bf16)acc[i][jj][1],
                    (__bf16)acc[i][jj][2], (__bf16)acc[i][jj][3]};
        *(bf16x4*)(stage + (size_t)d * 136 + sl) = o;
      }
    }
    __syncthreads();
    __bf16* VtH = Vt + (((size_t)b * 4 + (jb - 20)) * 128) * 2048;
#pragma unroll
    for (int p = 0; p < 8; ++p) {
      int d = p * 16 + orow;
      *(bf16x8*)(VtH + (size_t)d * 2048 + s0 + ocol) =
          *(const bf16x8*)(stage + (size_t)d * 136 + ocol);
    }
    return;
  }

  // Q/K: RMSNorm + RoPE, stage[s_local][d] (stride 136).
  const float* wt = (jb < 16) ? qw : kw;
  float wv[4];
#pragma unroll
  for (int jj = 0; jj < 4; ++jj) wv[jj] = 1.0f + wt[jj * 32 + wnh + c15];

#pragma unroll
  for (int i = 0; i < 4; ++i)
#pragma unroll
    for (int r = 0; r < 4; ++r) {
      float p = acc[i][0][r] * acc[i][0][r] + acc[i][1][r] * acc[i][1][r] +
                acc[i][2][r] * acc[i][2][r] + acc[i][3][r] * acc[i][3][r];
      p += __shfl_xor(p, 1);
      p += __shfl_xor(p, 2);
      p += __shfl_xor(p, 4);
      p += __shfl_xor(p, 8);
      if (c15 == 0) ssum[wm + i * 16 + quad * 4 + r][wnh >> 4] = p;
    }
  __syncthreads();

  const float QSC = 0.08838834764831845f * 1.4426950408889634f;  // scale * log2(e)
  const float post = (jb < 16) ? QSC : 1.0f;

#pragma unroll
  for (int i = 0; i < 4; ++i)
#pragma unroll
    for (int r = 0; r < 4; ++r) {
      int sl = wm + i * 16 + quad * 4 + r;
      int s = s0 + sl;
      float tot = ssum[sl][0] + ssum[sl][1];
      float rn = rsqrtf(tot * (1.0f / 128.0f) + 1e-8f) * post;
      __bf16* srow = stage + (size_t)sl * 136;
#pragma unroll
      for (int jj = 0; jj < 2; ++jj) {
        int dlo = jj * 32 + wnh + c15;
        float c = cosT[(size_t)s * 128 + dlo];   // cos[s][d] == cos[s][d+64]
        float sn = sinT[(size_t)s * 128 + dlo];
        float alo = acc[i][jj][r] * wv[jj];
        float ahi = acc[i][jj + 2][r] * wv[jj + 2];
        srow[dlo]      = (__bf16)((alo * c - ahi * sn) * rn);
        srow[dlo + 64] = (__bf16)((ahi * c + alo * sn) * rn);
      }
    }
  __syncthreads();

  __bf16* dstH = (jb < 16) ? Qb + (((size_t)b * 16 + jb) * 2048) * 128
                           : Kb + (((size_t)b * 4 + (jb - 16)) * 2048) * 128;
#pragma unroll
  for (int p = 0; p < 8; ++p) {
    int sl = p * 16 + orow;
    *(bf16x8*)(dstH + (size_t)(s0 + sl) * 128 + ocol) =
        *(const bf16x8*)(stage + (size_t)sl * 136 + ocol);
  }
}

// ---------------- m97-style bf16 GEMM (output projection) ----------------
__global__ __launch_bounds__(256) void gemm_bt(const __bf16* __restrict__ A,
                                               const __bf16* __restrict__ Bt,
                                               float* __restrict__ C,
                                               int M, int N, int K) {
  __shared__ __align__(16) __bf16 As[128 * 32];
  __shared__ __align__(16) __bf16 Bs[128 * 32];
  const int tid = threadIdx.x;
  const int lane = tid & 63;
  const int c15 = lane & 15, quad = lane >> 4;
  const int wm = ((tid >> 6) & 1) * 64;
  const int wn = (tid >> 7) * 64;
  const int m0 = blockIdx.y * 128, n0 = blockIdx.x * 128;
  const int wbase = tid & 192;

  f32x4 acc[4][4] = {};

  const int row0 = tid >> 2, cc0 = (tid & 3) * 8;
  const int row1 = (tid + 256) >> 2;
  const __bf16* a0 = A + (size_t)(m0 + row0) * K + cc0;
  const __bf16* a1 = A + (size_t)(m0 + row1) * K + cc0;
  const __bf16* b0 = Bt + (size_t)(n0 + row0) * K + cc0;
  const __bf16* b1 = Bt + (size_t)(n0 + row1) * K + cc0;
  __bf16* lA0 = As + (size_t)wbase * 8;
  __bf16* lA1 = As + (size_t)(256 + wbase) * 8;
  __bf16* lB0 = Bs + (size_t)wbase * 8;
  __bf16* lB1 = Bs + (size_t)(256 + wbase) * 8;

  for (int k0 = 0; k0 < K; k0 += 32) {
    gload_lds16(a0 + k0, lA0);
    gload_lds16(a1 + k0, lA1);
    gload_lds16(b0 + k0, lB0);
    gload_lds16(b1 + k0, lB1);
    __syncthreads();
    bf16x8 af[4], bfr[4];
#pragma unroll
    for (int i = 0; i < 4; ++i) {
      af[i]  = *(const bf16x8*)(As + (wm + i * 16 + c15) * 32 + quad * 8);
      bfr[i] = *(const bf16x8*)(Bs + (wn + i * 16 + c15) * 32 + quad * 8);
    }
#pragma unroll
    for (int i = 0; i < 4; ++i)
#pragma unroll
      for (int j = 0; j < 4; ++j)
        acc[i][j] = __builtin_amdgcn_mfma_f32_16x16x32_bf16(af[i], bfr[j], acc[i][j], 0, 0, 0);
    __syncthreads();
  }

#pragma unroll
  for (int i = 0; i < 4; ++i) {
    int r0 = m0 + wm + i * 16 + quad * 4;
#pragma unroll
    for (int j = 0; j < 4; ++j) {
      int cc = n0 + wn + j * 16 + c15;
#pragma unroll
      for (int r = 0; r < 4; ++r)
        C[(size_t)(r0 + r) * N + cc] = acc[i][j][r];
    }
  }
}

// ---------------- Flash attention v3: no-max softmax (exp2, m==0) ----------------
__global__ __launch_bounds__(256) void attn(
    const __bf16* __restrict__ Qb, const __bf16* __restrict__ Kb,
    const __bf16* __restrict__ Vt, const unsigned char* __restrict__ pad,
    const unsigned char* __restrict__ pad64, const int* __restrict__ winp,
    __bf16* __restrict__ O) {
  const int S = 2048;
  __shared__ __align__(16) __bf16 Ks[64 * 128];
  __shared__ __align__(16) __bf16 Vs[128 * 64];
  __shared__ __align__(16) __bf16 Ps[4 * 16 * 72];
  const int tid = threadIdx.x, w = tid >> 6, lane = tid & 63;
  const int c15 = lane & 15, quad = lane >> 4;
  const int q0 = (gridDim.x - 1 - blockIdx.x) * 16;
  const int kv = blockIdx.y, b = blockIdx.z;
  const int h = kv * 4 + w;
  const int W = *winp;
  const unsigned char* padb = pad + (size_t)b * S;
  const unsigned char* pad64b = pad64 + b * 32;
  const __bf16* Qh = Qb + (((size_t)b * 16 + h) * S) * 128;
  const __bf16* Kh = Kb + (((size_t)b * 4 + kv) * S) * 128;
  const __bf16* Vh = Vt + (((size_t)b * 4 + kv) * 128) * (size_t)S;
  __bf16* Pw = Ps + w * 16 * 72;

  bf16x8 qf[4];
#pragma unroll
  for (int c = 0; c < 4; ++c)
    qf[c] = *(const bf16x8*)(Qh + (size_t)(q0 + c15) * 128 + c * 32 + quad * 8);

  f32x4 acc[8] = {};
  float lsum[4] = {0.f, 0.f, 0.f, 0.f};

  const int krow_i = lane >> 4, kch = lane & 15;
  const int vrow_i = lane >> 3, vch = lane & 7;

  int kb0 = q0 - W; if (kb0 < 0) kb0 = 0; kb0 &= ~63;

  for (int kb = kb0; kb <= q0 + 15; kb += 64) {
    __syncthreads();
#pragma unroll
    for (int i = 0; i < 4; ++i) {
      int row = w * 16 + i * 4 + krow_i;
      gload_lds16(Kh + (size_t)(kb + row) * 128 + ((kch ^ (row & 15)) * 8),
                  Ks + (w * 16 + i * 4) * 128);
    }
#pragma unroll
    for (int i = 0; i < 4; ++i) {
      int row = w * 32 + i * 8 + vrow_i;
      gload_lds16(Vh + (size_t)row * S + kb + ((vch ^ (row & 7)) * 8),
                  Vs + (w * 32 + i * 8) * 64);
    }
    __syncthreads();

    f32x4 sf[4];
#pragma unroll
    for (int nb = 0; nb < 4; ++nb) {
      f32x4 cacc = {};
#pragma unroll
      for (int c = 0; c < 4; ++c) {
        bf16x8 kf = *(const bf16x8*)(Ks + (nb * 16 + c15) * 128 + (((c * 4 + quad) ^ c15) * 8));
        cacc = __builtin_amdgcn_mfma_f32_16x16x32_bf16(qf[c], kf, cacc, 0, 0, 0);
      }
      sf[nb] = cacc;
    }

    const bool fast = (kb + 63 <= q0) && (q0 + 15 - kb <= W) && (pad64b[kb >> 6] == 0);
    if (fast) {
#pragma unroll
      for (int r = 0; r < 4; ++r) {
        float p0 = exp2f(sf[0][r]), p1 = exp2f(sf[1][r]);
        float p2 = exp2f(sf[2][r]), p3 = exp2f(sf[3][r]);
        lsum[r] += (p0 + p1) + (p2 + p3);
        int pr = (quad * 4 + r) * 72 + c15;
        Pw[pr] = (__bf16)p0; Pw[pr + 16] = (__bf16)p1;
        Pw[pr + 32] = (__bf16)p2; Pw[pr + 48] = (__bf16)p3;
      }
    } else {
#pragma unroll
      for (int r = 0; r < 4; ++r) {
        const int qi = q0 + quad * 4 + r;
        float p[4];
#pragma unroll
        for (int nb = 0; nb < 4; ++nb) {
          int ki = kb + nb * 16 + c15;
          bool ok = (ki <= qi) && ((qi - ki) <= W) && (padb[ki] == 0);
          float e = exp2f(sf[nb][r]);
          p[nb] = ok ? e : 0.0f;
        }
        lsum[r] += (p[0] + p[1]) + (p[2] + p[3]);
        int pr = (quad * 4 + r) * 72 + c15;
        Pw[pr] = (__bf16)p[0]; Pw[pr + 16] = (__bf16)p[1];
        Pw[pr + 32] = (__bf16)p[2]; Pw[pr + 48] = (__bf16)p[3];
      }
    }

    bf16x8 pf0 = *(const bf16x8*)(Pw + c15 * 72 + quad * 8);
    bf16x8 pf1 = *(const bf16x8*)(Pw + c15 * 72 + 32 + quad * 8);
#pragma unroll
    for (int nb = 0; nb < 8; ++nb) {
      int row = nb * 16 + c15;
      bf16x8 vf0 = *(const bf16x8*)(Vs + row * 64 + ((quad ^ (c15 & 7)) * 8));
      bf16x8 vf1 = *(const bf16x8*)(Vs + row * 64 + (((4 + quad) ^ (c15 & 7)) * 8));
      acc[nb] = __builtin_amdgcn_mfma_f32_16x16x32_bf16(pf0, vf0, acc[nb], 0, 0, 0);
      acc[nb] = __builtin_amdgcn_mfma_f32_16x16x32_bf16(pf1, vf1, acc[nb], 0, 0, 0);
    }
  }

#pragma unroll
  for (int r = 0; r < 4; ++r) {
    lsum[r] += __shfl_xor(lsum[r], 1);
    lsum[r] += __shfl_xor(lsum[r], 2);
    lsum[r] += __shfl_xor(lsum[r], 4);
    lsum[r] += __shfl_xor(lsum[r], 8);
  }
  float inv[4];
#pragma unroll
  for (int r = 0; r < 4; ++r) inv[r] = 1.0f / lsum[r];
#pragma unroll
  for (int nb = 0; nb < 8; ++nb)
#pragma unroll
    for (int r = 0; r < 4; ++r) {
      size_t idx = ((size_t)b * S + q0 + quad * 4 + r) * 2048 + h * 128 + nb * 16 + c15;
      O[idx] = (__bf16)(acc[nb][r] * inv[r]);
    }
}

// ---------------- launch ----------------
extern "C" void kernel_launch(void* const* d_in, const int* in_sizes, int n_in,
                              void* d_out, int out_size, void* d_ws, size_t ws_size,
                              hipStream_t stream) {
  const float* x    = (const float*)d_in[0];
  const float* Wq   = (const float*)d_in[1];
  const float* Wk   = (const float*)d_in[2];
  const float* Wv   = (const float*)d_in[3];
  const float* Wo   = (const float*)d_in[4];
  const float* qw   = (const float*)d_in[5];
  const float* kw   = (const float*)d_in[6];
  const float* cosT = (const float*)d_in[7];
  const float* sinT = (const float*)d_in[8];
  const unsigned char* pad = (const unsigned char*)d_in[9];
  const int* win    = (const int*)d_in[10];

  char* ws = (char*)d_ws;
  __bf16* xb    = (__bf16*)(ws + 0);          // 4096x2048 bf16        (16 MB)
  __bf16* Wqkvt = (__bf16*)(ws + 16777216);   // 3072x2048 bf16        (12 MB)
  __bf16* Wot   = (__bf16*)(ws + 29360128);   // 2048x2048 bf16        (8 MB)
  __bf16* Qb    = (__bf16*)(ws + 37748736);   // [2][16][2048][128]    (16 MB)
  __bf16* Kb    = (__bf16*)(ws + 54525952);   // [2][4][2048][128]     (4 MB)
  __bf16* Vt    = (__bf16*)(ws + 58720256);   // [2][4][128][2048]     (4 MB)
  __bf16* Ob    = (__bf16*)(ws + 62914560);   // 4096x2048 bf16        (16 MB)
  unsigned char* pad64 = (unsigned char*)(ws + 79691776);  // [2][32]

  prep<<<dim3(288, 64, 1), dim3(32, 8, 1), 0, stream>>>(
      Wq, Wk, Wv, Wo, (const float4*)x, (const unsigned long long*)pad,
      Wqkvt, Wot, (bf16x4*)xb, pad64);

  gemm_qkv<<<dim3(24, 32, 1), 256, 0, stream>>>(
      xb, Wqkvt, qw, kw, cosT, sinT, Qb, Kb, Vt);

  attn<<<dim3(128, 4, 2), 256, 0, stream>>>(Qb, Kb, Vt, pad, pad64, win, Ob);

  gemm_bt<<<dim3(16, 32, 1), 256, 0, stream>>>(Ob, Wot, (float*)d_out, 4096, 2048, 2048);
}

// Round 6
// 339.439 us; speedup vs baseline: 1.0586x; 1.0586x over previous
//
#include <hip/hip_runtime.h>

typedef __attribute__((ext_vector_type(4))) float f32x4;
typedef __attribute__((ext_vector_type(8))) __bf16 bf16x8;
typedef __attribute__((ext_vector_type(4))) __bf16 bf16x4;

__device__ __forceinline__ void gload_lds16(const __bf16* g, __bf16* l) {
  __builtin_amdgcn_global_load_lds(
      (const __attribute__((address_space(1))) unsigned int*)(g),
      (__attribute__((address_space(3))) unsigned int*)(l), 16, 0, 0);
}

// ---------------- prep: weight transposes + x convert + pad_or, one launch --------
__global__ __launch_bounds__(256) void prep(
    const float* __restrict__ Wq, const float* __restrict__ Wk,
    const float* __restrict__ Wv, const float* __restrict__ Wo,
    const float4* __restrict__ x, const unsigned long long* __restrict__ pad,
    __bf16* __restrict__ Wqkvt, __bf16* __restrict__ Wot,
    bf16x4* __restrict__ xb, unsigned char* __restrict__ pad64) {
  const int bx = blockIdx.x, by = blockIdx.y;
  const int tx = threadIdx.x, ty = threadIdx.y;
  const int tid = ty * 32 + tx;
  if (bx >= 160) {
    int i = ((bx - 160) * 64 + by) * 256 + tid;
    float4 v = x[i];
    bf16x4 o = {(__bf16)v.x, (__bf16)v.y, (__bf16)v.z, (__bf16)v.w};
    xb[i] = o;
    return;
  }
  if (bx == 0 && by == 0 && tid < 64) {
    unsigned long long acc = 0;
#pragma unroll
    for (int i = 0; i < 8; ++i) acc |= pad[tid * 8 + i];
    pad64[tid] = (acc != 0) ? 1 : 0;
  }
  __shared__ float t[32][33];
  const float* src; __bf16* dst; int ss, c0;
  if (bx < 64)      { src = Wq; dst = Wqkvt;                       ss = 2048; c0 = bx * 32; }
  else if (bx < 80) { src = Wk; dst = Wqkvt + (size_t)2048 * 2048; ss = 512;  c0 = (bx - 64) * 32; }
  else if (bx < 96) { src = Wv; dst = Wqkvt + (size_t)2560 * 2048; ss = 512;  c0 = (bx - 80) * 32; }
  else              { src = Wo; dst = Wot;                         ss = 2048; c0 = (bx - 96) * 32; }
  const int r0 = by * 32;
#pragma unroll
  for (int i = ty; i < 32; i += 8)
    t[i][tx] = src[(size_t)(r0 + i) * ss + c0 + tx];
  __syncthreads();
#pragma unroll
  for (int i = ty; i < 32; i += 8)
    dst[(size_t)(c0 + i) * 2048 + r0 + tx] = (__bf16)t[tx][i];
}

// ---------------- QKV GEMM, plain K-loop (gemm_bt mapping), bf16 staged output ----
// C = xb[4096][2048] * Wqkvt[3072][2048]^T, tile 128x128, grid (24, 32).
// jb 0-15: Q head (raw, pre-norm), 16-19: K head (raw), 20-23: V stored transposed.
// Norm/RoPE is a separate pass (R5's fused epilogue caused the 82->103us regression:
// cos/sin gathers + ssum barriers + register pressure starved the K-loop).
__global__ __launch_bounds__(256) void gemm_qkv(
    const __bf16* __restrict__ A, const __bf16* __restrict__ Bt,
    __bf16* __restrict__ Qb, __bf16* __restrict__ Kb, __bf16* __restrict__ Vt) {
  __shared__ __align__(16) __bf16 smem[128 * 136];  // As|Bs in K-loop, stage in epilogue
  __bf16* As = smem;
  __bf16* Bs = smem + 128 * 32;
  __bf16* stage = smem;
  const int K = 2048;
  const int tid = threadIdx.x;
  const int lane = tid & 63;
  const int c15 = lane & 15, quad = lane >> 4;
  const int wm = ((tid >> 6) & 1) * 64;
  const int wn = (tid >> 7) * 64;
  const int jb = blockIdx.x;
  const int m0 = blockIdx.y * 128, n0 = jb * 128;
  const int wbase = tid & 192;

  f32x4 acc[4][4] = {};

  const int row0 = tid >> 2, cc0 = (tid & 3) * 8;
  const int row1 = (tid + 256) >> 2;
  const __bf16* a0 = A + (size_t)(m0 + row0) * K + cc0;
  const __bf16* a1 = A + (size_t)(m0 + row1) * K + cc0;
  const __bf16* b0 = Bt + (size_t)(n0 + row0) * K + cc0;
  const __bf16* b1 = Bt + (size_t)(n0 + row1) * K + cc0;
  __bf16* lA0 = As + (size_t)wbase * 8;
  __bf16* lA1 = As + (size_t)(256 + wbase) * 8;
  __bf16* lB0 = Bs + (size_t)wbase * 8;
  __bf16* lB1 = Bs + (size_t)(256 + wbase) * 8;

  for (int k0 = 0; k0 < K; k0 += 32) {
    gload_lds16(a0 + k0, lA0);
    gload_lds16(a1 + k0, lA1);
    gload_lds16(b0 + k0, lB0);
    gload_lds16(b1 + k0, lB1);
    __syncthreads();
    bf16x8 af[4], bfr[4];
#pragma unroll
    for (int i = 0; i < 4; ++i) {
      af[i]  = *(const bf16x8*)(As + (wm + i * 16 + c15) * 32 + quad * 8);
      bfr[i] = *(const bf16x8*)(Bs + (wn + i * 16 + c15) * 32 + quad * 8);
    }
#pragma unroll
    for (int i = 0; i < 4; ++i)
#pragma unroll
      for (int j = 0; j < 4; ++j)
        acc[i][j] = __builtin_amdgcn_mfma_f32_16x16x32_bf16(af[i], bfr[j], acc[i][j], 0, 0, 0);
    __syncthreads();
  }

  const int b = m0 >> 11;
  const int s0 = m0 & 2047;
  const int orow = tid >> 4, ocol = (tid & 15) * 8;  // out pass: 16 lanes = 256B line

  if (jb >= 20) {
    // V: stage[d][s_local] (stride 136), pack 4 consecutive s per ds_write_b64.
#pragma unroll
    for (int j = 0; j < 4; ++j) {
      int d = wn + j * 16 + c15;
#pragma unroll
      for (int i = 0; i < 4; ++i) {
        int sl = wm + i * 16 + quad * 4;
        bf16x4 o = {(__bf16)acc[i][j][0], (__bf16)acc[i][j][1],
                    (__bf16)acc[i][j][2], (__bf16)acc[i][j][3]};
        *(bf16x4*)(stage + (size_t)d * 136 + sl) = o;
      }
    }
    __syncthreads();
    __bf16* VtH = Vt + (((size_t)b * 4 + (jb - 20)) * 128) * 2048;
#pragma unroll
    for (int p = 0; p < 8; ++p) {
      int d = p * 16 + orow;
      *(bf16x8*)(VtH + (size_t)d * 2048 + s0 + ocol) =
          *(const bf16x8*)(stage + (size_t)d * 136 + ocol);
    }
    return;
  }

  // Q/K: raw bf16, stage[s_local][d] (stride 136), coalesced lines out.
#pragma unroll
  for (int i = 0; i < 4; ++i)
#pragma unroll
    for (int j = 0; j < 4; ++j)
#pragma unroll
      for (int r = 0; r < 4; ++r)
        stage[(size_t)(wm + i * 16 + quad * 4 + r) * 136 + wn + j * 16 + c15] =
            (__bf16)acc[i][j][r];
  __syncthreads();
  __bf16* dstH = (jb < 16) ? Qb + (((size_t)b * 16 + jb) * 2048) * 128
                           : Kb + (((size_t)b * 4 + (jb - 16)) * 2048) * 128;
#pragma unroll
  for (int p = 0; p < 8; ++p) {
    int sl = p * 16 + orow;
    *(bf16x8*)(dstH + (size_t)(s0 + sl) * 128 + ocol) =
        *(const bf16x8*)(stage + (size_t)sl * 136 + ocol);
  }
}

// ---------------- RMSNorm + RoPE, in-place on bf16 Q/K ----------------
// One wave per 128-elem head vector; lane owns (d, d+64) = the rotate-half pair.
// Q vectors v<65536, K vectors v>=65536. Q pre-scaled by softmax_scale*log2(e).
__global__ __launch_bounds__(256) void norm_rope(
    __bf16* __restrict__ Qb, __bf16* __restrict__ Kb,
    const float* __restrict__ qw, const float* __restrict__ kw,
    const float* __restrict__ cosT, const float* __restrict__ sinT) {
  const int tid = threadIdx.x, w = tid >> 6, lane = tid & 63;
  const int v = blockIdx.x * 4 + w;
  const bool isQ = v < 65536;
  __bf16* base = isQ ? Qb + (size_t)v * 128 : Kb + (size_t)(v - 65536) * 128;
  const int s = v & 2047;
  float x1 = (float)base[lane], x2 = (float)base[lane + 64];
  float ss = x1 * x1 + x2 * x2;
#pragma unroll
  for (int d = 32; d; d >>= 1) ss += __shfl_xor(ss, d);
  float rn = rsqrtf(ss * (1.0f / 128.0f) + 1e-8f);
  const float* wt = isQ ? qw : kw;
  float n1 = x1 * rn * (1.0f + wt[lane]);
  float n2 = x2 * rn * (1.0f + wt[lane + 64]);
  float c1 = cosT[s * 128 + lane], c2 = cosT[s * 128 + 64 + lane];
  float s1 = sinT[s * 128 + lane], s2 = sinT[s * 128 + 64 + lane];
  const float QSC = 0.08838834764831845f * 1.4426950408889634f;  // scale * log2(e)
  float post = isQ ? QSC : 1.0f;
  base[lane]      = (__bf16)((n1 * c1 - n2 * s1) * post);
  base[lane + 64] = (__bf16)((n2 * c2 + n1 * s2) * post);
}

// ---------------- m97-style bf16 GEMM (output projection) ----------------
__global__ __launch_bounds__(256) void gemm_bt(const __bf16* __restrict__ A,
                                               const __bf16* __restrict__ Bt,
                                               float* __restrict__ C,
                                               int M, int N, int K) {
  __shared__ __align__(16) __bf16 As[128 * 32];
  __shared__ __align__(16) __bf16 Bs[128 * 32];
  const int tid = threadIdx.x;
  const int lane = tid & 63;
  const int c15 = lane & 15, quad = lane >> 4;
  const int wm = ((tid >> 6) & 1) * 64;
  const int wn = (tid >> 7) * 64;
  const int m0 = blockIdx.y * 128, n0 = blockIdx.x * 128;
  const int wbase = tid & 192;

  f32x4 acc[4][4] = {};

  const int row0 = tid >> 2, cc0 = (tid & 3) * 8;
  const int row1 = (tid + 256) >> 2;
  const __bf16* a0 = A + (size_t)(m0 + row0) * K + cc0;
  const __bf16* a1 = A + (size_t)(m0 + row1) * K + cc0;
  const __bf16* b0 = Bt + (size_t)(n0 + row0) * K + cc0;
  const __bf16* b1 = Bt + (size_t)(n0 + row1) * K + cc0;
  __bf16* lA0 = As + (size_t)wbase * 8;
  __bf16* lA1 = As + (size_t)(256 + wbase) * 8;
  __bf16* lB0 = Bs + (size_t)wbase * 8;
  __bf16* lB1 = Bs + (size_t)(256 + wbase) * 8;

  for (int k0 = 0; k0 < K; k0 += 32) {
    gload_lds16(a0 + k0, lA0);
    gload_lds16(a1 + k0, lA1);
    gload_lds16(b0 + k0, lB0);
    gload_lds16(b1 + k0, lB1);
    __syncthreads();
    bf16x8 af[4], bfr[4];
#pragma unroll
    for (int i = 0; i < 4; ++i) {
      af[i]  = *(const bf16x8*)(As + (wm + i * 16 + c15) * 32 + quad * 8);
      bfr[i] = *(const bf16x8*)(Bs + (wn + i * 16 + c15) * 32 + quad * 8);
    }
#pragma unroll
    for (int i = 0; i < 4; ++i)
#pragma unroll
      for (int j = 0; j < 4; ++j)
        acc[i][j] = __builtin_amdgcn_mfma_f32_16x16x32_bf16(af[i], bfr[j], acc[i][j], 0, 0, 0);
    __syncthreads();
  }

#pragma unroll
  for (int i = 0; i < 4; ++i) {
    int r0 = m0 + wm + i * 16 + quad * 4;
#pragma unroll
    for (int j = 0; j < 4; ++j) {
      int cc = n0 + wn + j * 16 + c15;
#pragma unroll
      for (int r = 0; r < 4; ++r)
        C[(size_t)(r0 + r) * N + cc] = acc[i][j][r];
    }
  }
}

// ---------------- Flash attention v3: no-max softmax (exp2, m==0) ----------------
__global__ __launch_bounds__(256) void attn(
    const __bf16* __restrict__ Qb, const __bf16* __restrict__ Kb,
    const __bf16* __restrict__ Vt, const unsigned char* __restrict__ pad,
    const unsigned char* __restrict__ pad64, const int* __restrict__ winp,
    __bf16* __restrict__ O) {
  const int S = 2048;
  __shared__ __align__(16) __bf16 Ks[64 * 128];
  __shared__ __align__(16) __bf16 Vs[128 * 64];
  __shared__ __align__(16) __bf16 Ps[4 * 16 * 72];
  const int tid = threadIdx.x, w = tid >> 6, lane = tid & 63;
  const int c15 = lane & 15, quad = lane >> 4;
  const int q0 = (gridDim.x - 1 - blockIdx.x) * 16;
  const int kv = blockIdx.y, b = blockIdx.z;
  const int h = kv * 4 + w;
  const int W = *winp;
  const unsigned char* padb = pad + (size_t)b * S;
  const unsigned char* pad64b = pad64 + b * 32;
  const __bf16* Qh = Qb + (((size_t)b * 16 + h) * S) * 128;
  const __bf16* Kh = Kb + (((size_t)b * 4 + kv) * S) * 128;
  const __bf16* Vh = Vt + (((size_t)b * 4 + kv) * 128) * (size_t)S;
  __bf16* Pw = Ps + w * 16 * 72;

  bf16x8 qf[4];
#pragma unroll
  for (int c = 0; c < 4; ++c)
    qf[c] = *(const bf16x8*)(Qh + (size_t)(q0 + c15) * 128 + c * 32 + quad * 8);

  f32x4 acc[8] = {};
  float lsum[4] = {0.f, 0.f, 0.f, 0.f};

  const int krow_i = lane >> 4, kch = lane & 15;
  const int vrow_i = lane >> 3, vch = lane & 7;

  int kb0 = q0 - W; if (kb0 < 0) kb0 = 0; kb0 &= ~63;

  for (int kb = kb0; kb <= q0 + 15; kb += 64) {
    __syncthreads();
#pragma unroll
    for (int i = 0; i < 4; ++i) {
      int row = w * 16 + i * 4 + krow_i;
      gload_lds16(Kh + (size_t)(kb + row) * 128 + ((kch ^ (row & 15)) * 8),
                  Ks + (w * 16 + i * 4) * 128);
    }
#pragma unroll
    for (int i = 0; i < 4; ++i) {
      int row = w * 32 + i * 8 + vrow_i;
      gload_lds16(Vh + (size_t)row * S + kb + ((vch ^ (row & 7)) * 8),
                  Vs + (w * 32 + i * 8) * 64);
    }
    __syncthreads();

    f32x4 sf[4];
#pragma unroll
    for (int nb = 0; nb < 4; ++nb) {
      f32x4 cacc = {};
#pragma unroll
      for (int c = 0; c < 4; ++c) {
        bf16x8 kf = *(const bf16x8*)(Ks + (nb * 16 + c15) * 128 + (((c * 4 + quad) ^ c15) * 8));
        cacc = __builtin_amdgcn_mfma_f32_16x16x32_bf16(qf[c], kf, cacc, 0, 0, 0);
      }
      sf[nb] = cacc;
    }

    const bool fast = (kb + 63 <= q0) && (q0 + 15 - kb <= W) && (pad64b[kb >> 6] == 0);
    if (fast) {
#pragma unroll
      for (int r = 0; r < 4; ++r) {
        float p0 = exp2f(sf[0][r]), p1 = exp2f(sf[1][r]);
        float p2 = exp2f(sf[2][r]), p3 = exp2f(sf[3][r]);
        lsum[r] += (p0 + p1) + (p2 + p3);
        int pr = (quad * 4 + r) * 72 + c15;
        Pw[pr] = (__bf16)p0; Pw[pr + 16] = (__bf16)p1;
        Pw[pr + 32] = (__bf16)p2; Pw[pr + 48] = (__bf16)p3;
      }
    } else {
#pragma unroll
      for (int r = 0; r < 4; ++r) {
        const int qi = q0 + quad * 4 + r;
        float p[4];
#pragma unroll
        for (int nb = 0; nb < 4; ++nb) {
          int ki = kb + nb * 16 + c15;
          bool ok = (ki <= qi) && ((qi - ki) <= W) && (padb[ki] == 0);
          float e = exp2f(sf[nb][r]);
          p[nb] = ok ? e : 0.0f;
        }
        lsum[r] += (p[0] + p[1]) + (p[2] + p[3]);
        int pr = (quad * 4 + r) * 72 + c15;
        Pw[pr] = (__bf16)p[0]; Pw[pr + 16] = (__bf16)p[1];
        Pw[pr + 32] = (__bf16)p[2]; Pw[pr + 48] = (__bf16)p[3];
      }
    }

    bf16x8 pf0 = *(const bf16x8*)(Pw + c15 * 72 + quad * 8);
    bf16x8 pf1 = *(const bf16x8*)(Pw + c15 * 72 + 32 + quad * 8);
#pragma unroll
    for (int nb = 0; nb < 8; ++nb) {
      int row = nb * 16 + c15;
      bf16x8 vf0 = *(const bf16x8*)(Vs + row * 64 + ((quad ^ (c15 & 7)) * 8));
      bf16x8 vf1 = *(const bf16x8*)(Vs + row * 64 + (((4 + quad) ^ (c15 & 7)) * 8));
      acc[nb] = __builtin_amdgcn_mfma_f32_16x16x32_bf16(pf0, vf0, acc[nb], 0, 0, 0);
      acc[nb] = __builtin_amdgcn_mfma_f32_16x16x32_bf16(pf1, vf1, acc[nb], 0, 0, 0);
    }
  }

#pragma unroll
  for (int r = 0; r < 4; ++r) {
    lsum[r] += __shfl_xor(lsum[r], 1);
    lsum[r] += __shfl_xor(lsum[r], 2);
    lsum[r] += __shfl_xor(lsum[r], 4);
    lsum[r] += __shfl_xor(lsum[r], 8);
  }
  float inv[4];
#pragma unroll
  for (int r = 0; r < 4; ++r) inv[r] = 1.0f / lsum[r];
#pragma unroll
  for (int nb = 0; nb < 8; ++nb)
#pragma unroll
    for (int r = 0; r < 4; ++r) {
      size_t idx = ((size_t)b * S + q0 + quad * 4 + r) * 2048 + h * 128 + nb * 16 + c15;
      O[idx] = (__bf16)(acc[nb][r] * inv[r]);
    }
}

// ---------------- launch ----------------
extern "C" void kernel_launch(void* const* d_in, const int* in_sizes, int n_in,
                              void* d_out, int out_size, void* d_ws, size_t ws_size,
                              hipStream_t stream) {
  const float* x    = (const float*)d_in[0];
  const float* Wq   = (const float*)d_in[1];
  const float* Wk   = (const float*)d_in[2];
  const float* Wv   = (const float*)d_in[3];
  const float* Wo   = (const float*)d_in[4];
  const float* qw   = (const float*)d_in[5];
  const float* kw   = (const float*)d_in[6];
  const float* cosT = (const float*)d_in[7];
  const float* sinT = (const float*)d_in[8];
  const unsigned char* pad = (const unsigned char*)d_in[9];
  const int* win    = (const int*)d_in[10];

  char* ws = (char*)d_ws;
  __bf16* xb    = (__bf16*)(ws + 0);          // 4096x2048 bf16        (16 MB)
  __bf16* Wqkvt = (__bf16*)(ws + 16777216);   // 3072x2048 bf16        (12 MB)
  __bf16* Wot   = (__bf16*)(ws + 29360128);   // 2048x2048 bf16        (8 MB)
  __bf16* Qb    = (__bf16*)(ws + 37748736);   // [2][16][2048][128]    (16 MB)
  __bf16* Kb    = (__bf16*)(ws + 54525952);   // [2][4][2048][128]     (4 MB)
  __bf16* Vt    = (__bf16*)(ws + 58720256);   // [2][4][128][2048]     (4 MB)
  __bf16* Ob    = (__bf16*)(ws + 62914560);   // 4096x2048 bf16        (16 MB)
  unsigned char* pad64 = (unsigned char*)(ws + 79691776);  // [2][32]

  prep<<<dim3(288, 64, 1), dim3(32, 8, 1), 0, stream>>>(
      Wq, Wk, Wv, Wo, (const float4*)x, (const unsigned long long*)pad,
      Wqkvt, Wot, (bf16x4*)xb, pad64);

  gemm_qkv<<<dim3(24, 32, 1), 256, 0, stream>>>(xb, Wqkvt, Qb, Kb, Vt);

  norm_rope<<<20480, 256, 0, stream>>>(Qb, Kb, qw, kw, cosT, sinT);

  attn<<<dim3(128, 4, 2), 256, 0, stream>>>(Qb, Kb, Vt, pad, pad64, win, Ob);

  gemm_bt<<<dim3(16, 32, 1), 256, 0, stream>>>(Ob, Wot, (float*)d_out, 4096, 2048, 2048);
}